// Round 1
// baseline (26.256 us; speedup 1.0000x reference)
//
#include <hip/hip_runtime.h>

#define BB 8
#define SS 4096
#define DD 1024
#define TEMP 0.1f
#define PADV -100.0f
#define EPSV 1e-8f

__global__ __launch_bounds__(256) void fill_kernel(float* __restrict__ out) {
    int i = blockIdx.x * 256 + threadIdx.x;   // grid covers 2*B*S exactly
    out[i] = PADV;
}

// One block (256 threads) per batch. Each thread scans 16 labels, block-scan
// gives the compacted write offset. Writes idx[b][j] (original position of
// j-th valid), cnt[b], and the valid labels (as float) into out_lab.
__global__ __launch_bounds__(256) void compact_kernel(const int* __restrict__ labels,
                                                      int* __restrict__ idx,
                                                      int* __restrict__ cnt,
                                                      float* __restrict__ out_lab) {
    int b = blockIdx.x;
    int t = threadIdx.x;
    const int* lab = labels + b * SS;

    int myl[16];
#pragma unroll
    for (int q = 0; q < 4; ++q) {
        int4 v = ((const int4*)lab)[t * 4 + q];
        myl[4 * q + 0] = v.x; myl[4 * q + 1] = v.y;
        myl[4 * q + 2] = v.z; myl[4 * q + 3] = v.w;
    }
    int mycnt = 0;
#pragma unroll
    for (int i = 0; i < 16; ++i) mycnt += (myl[i] != -100) ? 1 : 0;

    __shared__ int sh[256];
    sh[t] = mycnt;
    __syncthreads();
    // Hillis-Steele inclusive scan
    for (int off = 1; off < 256; off <<= 1) {
        int add = (t >= off) ? sh[t - off] : 0;
        __syncthreads();
        sh[t] += add;
        __syncthreads();
    }
    int base = sh[t] - mycnt;            // exclusive prefix
    if (t == 255) cnt[b] = sh[255];

    int o = base;
#pragma unroll
    for (int i = 0; i < 16; ++i) {
        if (myl[i] != -100) {
            idx[b * SS + o]     = t * 16 + i;
            out_lab[b * SS + o] = (float)myl[i];
            ++o;
        }
    }
}

// One block per (j, b); block = 256 threads, each owns one float4 of the
// 1024-dim vectors. Computes dot(x_j, x_next) and both squared norms.
__global__ __launch_bounds__(256) void cos_kernel(const float* __restrict__ x,
                                                  const int* __restrict__ idx,
                                                  const int* __restrict__ cnt,
                                                  float* __restrict__ out_cos) {
    int j = blockIdx.x;
    int b = blockIdx.y;
    int c = cnt[b];
    if (j >= c) return;
    int jn = (j + 1 == c) ? 0 : (j + 1);

    size_t basea = ((size_t)b * SS + (size_t)idx[b * SS + j])  * DD;
    size_t baseb = ((size_t)b * SS + (size_t)idx[b * SS + jn]) * DD;

    int t = threadIdx.x;
    float4 a = *(const float4*)(x + basea + (size_t)t * 4);
    float4 v = *(const float4*)(x + baseb + (size_t)t * 4);

    float dot = a.x * v.x + a.y * v.y + a.z * v.z + a.w * v.w;
    float na  = a.x * a.x + a.y * a.y + a.z * a.z + a.w * a.w;
    float nb  = v.x * v.x + v.y * v.y + v.z * v.z + v.w * v.w;

#pragma unroll
    for (int off = 32; off > 0; off >>= 1) {
        dot += __shfl_down(dot, off, 64);
        na  += __shfl_down(na,  off, 64);
        nb  += __shfl_down(nb,  off, 64);
    }

    __shared__ float sdot[4], sna[4], snb[4];
    int wave = t >> 6;
    if ((t & 63) == 0) { sdot[wave] = dot; sna[wave] = na; snb[wave] = nb; }
    __syncthreads();
    if (t == 0) {
        float d2 = sdot[0] + sdot[1] + sdot[2] + sdot[3];
        float n1 = sna[0]  + sna[1]  + sna[2]  + sna[3];
        float n2 = snb[0]  + snb[1]  + snb[2]  + snb[3];
        out_cos[b * SS + j] = d2 / fmaxf(sqrtf(n1) * sqrtf(n2), EPSV) / TEMP;
    }
}

extern "C" void kernel_launch(void* const* d_in, const int* in_sizes, int n_in,
                              void* d_out, int out_size, void* d_ws, size_t ws_size,
                              hipStream_t stream) {
    const float* seq   = (const float*)d_in[0];   // [B,S,D] f32
    const int*   labels= (const int*)d_in[1];     // [B,S] i32

    float* out_cos = (float*)d_out;               // [B,S]
    float* out_lab = (float*)d_out + BB * SS;     // [B,S] written as floats

    int* idx = (int*)d_ws;                        // B*S ints
    int* cnt = idx + BB * SS;                     // B ints

    // 1) pad both outputs with -100
    fill_kernel<<<(2 * BB * SS) / 256, 256, 0, stream>>>(out_cos);

    // 2) compact valid positions per batch
    compact_kernel<<<BB, 256, 0, stream>>>(labels, idx, cnt, out_lab);

    // 3) pairwise cosine over valid ranks
    dim3 grid(SS, BB);
    cos_kernel<<<grid, 256, 0, stream>>>(seq, idx, cnt, out_cos);
}

// Round 2
// 17.912 us; speedup vs baseline: 1.4658x; 1.4658x over previous
//
#include <hip/hip_runtime.h>

#define BB 8
#define SS 4096
#define DD 1024
#define TEMP 0.1f
#define PADV -100.0f
#define EPSV 1e-8f

// One block (1024 threads) per batch. Each thread scans 4 labels (int4),
// wave-level shfl scan + one LDS cross-wave combine gives compacted offsets.
// Writes idx[b][j], cnt[b], valid labels as float, AND the -100 pads for
// slots >= cnt (disjoint from valid slots, so no race).
__global__ __launch_bounds__(1024) void compact_kernel(const int* __restrict__ labels,
                                                       int* __restrict__ idx,
                                                       int* __restrict__ cnt,
                                                       float* __restrict__ out_lab) {
    int b = blockIdx.x;
    int t = threadIdx.x;
    int lane = t & 63, wave = t >> 6;

    int4 v = ((const int4*)(labels + b * SS))[t];
    int vals[4] = {v.x, v.y, v.z, v.w};
    int mycnt = (vals[0] != -100) + (vals[1] != -100) + (vals[2] != -100) + (vals[3] != -100);

    // inclusive scan within wave
    int scan = mycnt;
#pragma unroll
    for (int off = 1; off < 64; off <<= 1) {
        int n = __shfl_up(scan, off, 64);
        if (lane >= off) scan += n;
    }

    __shared__ int wsum[16];
    if (lane == 63) wsum[wave] = scan;
    __syncthreads();

    int wbase = 0, total = 0;
#pragma unroll
    for (int w = 0; w < 16; ++w) {
        int s = wsum[w];
        wbase += (w < wave) ? s : 0;
        total += s;
    }

    if (t == 0) cnt[b] = total;

    int o = wbase + scan - mycnt;   // exclusive prefix across block
#pragma unroll
    for (int i = 0; i < 4; ++i) {
        if (vals[i] != -100) {
            idx[b * SS + o]     = 4 * t + i;
            out_lab[b * SS + o] = (float)vals[i];
            ++o;
        }
    }
#pragma unroll
    for (int i = 0; i < 4; ++i) {
        int s = 4 * t + i;
        if (s >= total) out_lab[b * SS + s] = PADV;
    }
}

// One WAVE per pair: 64 lanes x 4 float4 = 1024 floats per vector.
// Butterfly shfl_xor reduce; no LDS, no syncthreads. Invalid ranks write PAD.
__global__ __launch_bounds__(256) void cos_kernel(const float* __restrict__ x,
                                                  const int* __restrict__ idx,
                                                  const int* __restrict__ cnt,
                                                  float* __restrict__ out_cos) {
    int b    = blockIdx.y;
    int lane = threadIdx.x & 63;
    int j    = blockIdx.x * 4 + (threadIdx.x >> 6);
    int c    = cnt[b];

    if (j >= c) {
        if (lane == 0) out_cos[b * SS + j] = PADV;
        return;
    }
    int jn = (j + 1 == c) ? 0 : (j + 1);
    const int* ib = idx + b * SS;
    const float* pa = x + ((size_t)b * SS + (size_t)ib[j])  * DD;
    const float* pb = x + ((size_t)b * SS + (size_t)ib[jn]) * DD;

    float dot = 0.f, na = 0.f, nb = 0.f;
#pragma unroll
    for (int q = 0; q < 4; ++q) {
        float4 a = *(const float4*)(pa + q * 256 + lane * 4);
        float4 w = *(const float4*)(pb + q * 256 + lane * 4);
        dot += a.x * w.x + a.y * w.y + a.z * w.z + a.w * w.w;
        na  += a.x * a.x + a.y * a.y + a.z * a.z + a.w * a.w;
        nb  += w.x * w.x + w.y * w.y + w.z * w.z + w.w * w.w;
    }
#pragma unroll
    for (int off = 32; off; off >>= 1) {
        dot += __shfl_xor(dot, off, 64);
        na  += __shfl_xor(na,  off, 64);
        nb  += __shfl_xor(nb,  off, 64);
    }
    if (lane == 0)
        out_cos[b * SS + j] = dot / fmaxf(sqrtf(na) * sqrtf(nb), EPSV) / TEMP;
}

extern "C" void kernel_launch(void* const* d_in, const int* in_sizes, int n_in,
                              void* d_out, int out_size, void* d_ws, size_t ws_size,
                              hipStream_t stream) {
    const float* seq    = (const float*)d_in[0];   // [B,S,D] f32
    const int*   labels = (const int*)d_in[1];     // [B,S] i32

    float* out_cos = (float*)d_out;                // [B,S]
    float* out_lab = (float*)d_out + BB * SS;      // [B,S] as floats

    int* idx = (int*)d_ws;                         // B*S ints
    int* cnt = idx + BB * SS;                      // B ints

    compact_kernel<<<BB, 1024, 0, stream>>>(labels, idx, cnt, out_lab);

    dim3 grid(SS / 4, BB);
    cos_kernel<<<grid, 256, 0, stream>>>(seq, idx, cnt, out_cos);
}